// Round 1
// baseline (741.100 us; speedup 1.0000x reference)
//
#include <hip/hip_runtime.h>
#include <math.h>

#define ENC 128
#define PRED 256
#define JD 256      // joiner_dim
#define VOCAB 500
#define BB 8
#define TT 256
#define UU 64

#define UH 32        // u rows per workgroup (half of U)
#define JSTRIDE 260  // joint LDS row stride (pad 4 -> conflict-free, 16B aligned)
#define VS 128       // vocab slice width
#define KBLK 16      // k block staged per iteration
#define WSTRIDE 132  // w2s LDS row stride (pad 4)

// ---------------- Kernel A: hf = ft @ w1f^T, hg = gu @ w1g^T ----------------
// hf: [B*T][256], hg: [B*U][256] into workspace. ~100M MACs total, negligible.
__global__ __launch_bounds__(256) void joiner_pre(const float* __restrict__ ft,
                                                  const float* __restrict__ gu,
                                                  const float* __restrict__ w1,
                                                  float* __restrict__ hf,
                                                  float* __restrict__ hg) {
    __shared__ float x[PRED];
    const int row = blockIdx.x;
    const int j = threadIdx.x;   // output column 0..255
    if (row < BB * TT) {
        if (j < ENC) x[j] = ft[row * ENC + j];
        __syncthreads();
        const float* wr = w1 + j * (ENC + PRED);
        float s = 0.f;
#pragma unroll
        for (int k = 0; k < ENC; k += 4) {
            float4 w4 = *(const float4*)(wr + k);
            s += w4.x * x[k] + w4.y * x[k + 1] + w4.z * x[k + 2] + w4.w * x[k + 3];
        }
        hf[row * JD + j] = s;
    } else {
        const int r = row - BB * TT;
        x[j] = gu[r * PRED + j];
        __syncthreads();
        const float* wr = w1 + j * (ENC + PRED) + ENC;
        float s = 0.f;
#pragma unroll
        for (int k = 0; k < PRED; k += 4) {
            float4 w4 = *(const float4*)(wr + k);
            s += w4.x * x[k] + w4.y * x[k + 1] + w4.z * x[k + 2] + w4.w * x[k + 3];
        }
        hg[r * JD + j] = s;
    }
}

// ---------------- Kernel B: out[bt][u][v] = tanh(hf+hg) @ w2^T ----------------
// One WG per (bt, u-half). joint[32][256] computed once into LDS, then
// 4 vocab slices x 16 k-blocks, w2 tile staged transposed in LDS.
__global__ __launch_bounds__(256, 3) void joiner_main(const float* __restrict__ hf,
                                                      const float* __restrict__ hg,
                                                      const float* __restrict__ w2,
                                                      float* __restrict__ out) {
    __shared__ float joint[UH * JSTRIDE];   // 33280 B
    __shared__ float w2s[KBLK * WSTRIDE];   // 8448 B  (total 41728 B -> 3 WG/CU)

    const int bid = blockIdx.x;
    const int bt = bid >> 1;       // 0..2047
    const int uh = bid & 1;        // which half of u
    const int b  = bt >> 8;        // batch index (T=256)
    const int tid = threadIdx.x;

    // ---- Phase 1: joint[u][k] = tanh(hf[bt][k] + hg[b*64 + uh*32 + u][k]) ----
    {
        const float hfk = hf[bt * JD + tid];                      // k = tid
        const float* hgp = hg + ((size_t)(b * UU + uh * UH)) * JD + tid;
#pragma unroll 4
        for (int u = 0; u < UH; ++u) {
            joint[u * JSTRIDE + tid] = tanhf(hfk + hgp[u * JD]);
        }
    }
    // (first __syncthreads inside the k-loop publishes joint)

    const int tu = tid >> 4;   // 0..15  -> u rows {tu, tu+16}
    const int tv = tid & 15;   // 0..15  -> v cols v0 + tv*8 .. +7

    float* outbase = out + (size_t)bt * UU * VOCAB + (size_t)(uh * UH) * VOCAB;

    for (int s = 0; s < 4; ++s) {
        const int v0 = s * VS;
        float acc[2][8];
#pragma unroll
        for (int i = 0; i < 2; ++i)
#pragma unroll
            for (int j = 0; j < 8; ++j) acc[i][j] = 0.f;

        for (int kb = 0; kb < JD; kb += KBLK) {
            __syncthreads();   // protects w2s reuse; first iter publishes joint
            // stage w2[v0:v0+128][kb:kb+16] transposed -> w2s[kk][vv]
#pragma unroll
            for (int r = 0; r < 2; ++r) {
                const int idx = tid + 256 * r;    // 0..511
                const int vv = idx >> 2;          // 0..127
                const int kq = idx & 3;           // float4 index within 16-k row
                const int v = v0 + vv;
                float4 f;
                if (v < VOCAB) f = *(const float4*)(w2 + (size_t)v * JD + kb + kq * 4);
                else           f = make_float4(0.f, 0.f, 0.f, 0.f);
                w2s[(kq * 4 + 0) * WSTRIDE + vv] = f.x;
                w2s[(kq * 4 + 1) * WSTRIDE + vv] = f.y;
                w2s[(kq * 4 + 2) * WSTRIDE + vv] = f.z;
                w2s[(kq * 4 + 3) * WSTRIDE + vv] = f.w;
            }
            __syncthreads();

#pragma unroll
            for (int q = 0; q < 4; ++q) {
                const int k4 = kb + q * 4;
                const float4 a0 = *(const float4*)(joint + tu * JSTRIDE + k4);
                const float4 a1 = *(const float4*)(joint + (tu + 16) * JSTRIDE + k4);
#pragma unroll
                for (int kk = 0; kk < 4; ++kk) {
                    const float* wrow = w2s + (q * 4 + kk) * WSTRIDE + tv * 8;
                    const float4 wlo = *(const float4*)(wrow);
                    const float4 whi = *(const float4*)(wrow + 4);
                    const float a0k = ((const float*)&a0)[kk];
                    const float a1k = ((const float*)&a1)[kk];
                    float w[8] = {wlo.x, wlo.y, wlo.z, wlo.w, whi.x, whi.y, whi.z, whi.w};
#pragma unroll
                    for (int j = 0; j < 8; ++j) {
                        acc[0][j] = fmaf(a0k, w[j], acc[0][j]);
                        acc[1][j] = fmaf(a1k, w[j], acc[1][j]);
                    }
                }
            }
        }

        // ---- store this vocab slice ----
#pragma unroll
        for (int i = 0; i < 2; ++i) {
            const int u = tu + 16 * i;
            float* o = outbase + (size_t)u * VOCAB + v0 + tv * 8;
            if (s < 3) {
                *(float4*)(o)     = make_float4(acc[i][0], acc[i][1], acc[i][2], acc[i][3]);
                *(float4*)(o + 4) = make_float4(acc[i][4], acc[i][5], acc[i][6], acc[i][7]);
            } else {
#pragma unroll
                for (int j = 0; j < 8; ++j) {
                    const int v = v0 + tv * 8 + j;
                    if (v < VOCAB) o[j] = acc[i][j];
                }
            }
        }
    }
}

extern "C" void kernel_launch(void* const* d_in, const int* in_sizes, int n_in,
                              void* d_out, int out_size, void* d_ws, size_t ws_size,
                              hipStream_t stream) {
    const float* ft = (const float*)d_in[0];
    const float* gu = (const float*)d_in[1];
    const float* w1 = (const float*)d_in[2];
    const float* w2 = (const float*)d_in[3];
    float* out = (float*)d_out;

    // workspace: hf [2048*256] floats, then hg [512*256] floats = 2.5 MB
    float* hf = (float*)d_ws;
    float* hg = hf + (size_t)BB * TT * JD;

    joiner_pre<<<BB * TT + BB * UU, 256, 0, stream>>>(ft, gu, w1, hf, hg);
    joiner_main<<<(BB * TT) * 2, 256, 0, stream>>>(hf, hg, w2, out);
}

// Round 3
// 238.840 us; speedup vs baseline: 3.1029x; 3.1029x over previous
//
#include <hip/hip_runtime.h>
#include <hip/hip_bf16.h>
#include <math.h>

#define ENC 128
#define PRED 256
#define JD 256      // joiner_dim
#define VOCAB 500
#define NPAD 512
#define BB 8
#define TT 256
#define UU 64

typedef __attribute__((ext_vector_type(8))) short bf16x8;
typedef __attribute__((ext_vector_type(4))) float f32x4;

static __device__ __forceinline__ ushort bf16_bits(float x) {
    __hip_bfloat16 h = __float2bfloat16(x);
    union { __hip_bfloat16 b; ushort u; } c; c.b = h;
    return c.u;
}

// ---------------- Kernel A: hf = ft @ w1f^T, hg = gu @ w1g^T (fp32) ----------
__global__ __launch_bounds__(256) void joiner_pre(const float* __restrict__ ft,
                                                  const float* __restrict__ gu,
                                                  const float* __restrict__ w1,
                                                  float* __restrict__ hf,
                                                  float* __restrict__ hg) {
    __shared__ float x[PRED];
    const int row = blockIdx.x;
    const int j = threadIdx.x;   // output column 0..255
    if (row < BB * TT) {
        if (j < ENC) x[j] = ft[row * ENC + j];
        __syncthreads();
        const float* wr = w1 + j * (ENC + PRED);
        float s = 0.f;
#pragma unroll
        for (int k = 0; k < ENC; k += 4) {
            float4 w4 = *(const float4*)(wr + k);
            s += w4.x * x[k] + w4.y * x[k + 1] + w4.z * x[k + 2] + w4.w * x[k + 3];
        }
        hf[row * JD + j] = s;
    } else {
        const int r = row - BB * TT;
        x[j] = gu[r * PRED + j];
        __syncthreads();
        const float* wr = w1 + j * (ENC + PRED) + ENC;
        float s = 0.f;
#pragma unroll
        for (int k = 0; k < PRED; k += 4) {
            float4 w4 = *(const float4*)(wr + k);
            s += w4.x * x[k] + w4.y * x[k + 1] + w4.z * x[k + 2] + w4.w * x[k + 3];
        }
        hg[r * JD + j] = s;
    }
}

// ---------------- Kernel B: split w2 (fp32) -> bf16 hi + bf16 lo, pad to 512 rows
__global__ __launch_bounds__(256) void w2split(const float* __restrict__ w2,
                                               ushort* __restrict__ w2h,
                                               ushort* __restrict__ w2l) {
    const int idx = blockIdx.x * 256 + threadIdx.x;  // 0 .. 512*256-1
    const int row = idx >> 8;
    const int col = idx & 255;
    float x = (row < VOCAB) ? w2[row * JD + col] : 0.f;
    __hip_bfloat16 h = __float2bfloat16(x);
    float hv = __bfloat162float(h);
    w2h[idx] = bf16_bits(x);           // hi = bf16(x)
    w2l[idx] = bf16_bits(x - hv);      // lo = bf16(x - hi)
}

// ---------------- Kernel C: out = tanh(hf+hg) @ w2^T via split-bf16 MFMA -----
// One WG (4 waves) per bt. Phase 1: joint 64x256 -> bf16 hi/lo in LDS
// (XOR-swizzled rows). Phase 2: wave w owns vocab slice [w*128, w*128+128);
// 16x16x32 bf16 MFMA, 3 passes (AhBh + AhBl + AlBh), fp32 accumulate.
__global__ __launch_bounds__(256, 2) void joiner_mfma(const float* __restrict__ hf,
                                                      const float* __restrict__ hg,
                                                      const ushort* __restrict__ w2h,
                                                      const ushort* __restrict__ w2l,
                                                      float* __restrict__ out) {
    __shared__ uint4 ldsv[4096];             // 64 KB: jh @0, jl @32768
    char* lds = (char*)ldsv;

    const int tid = threadIdx.x;
    const int bt = blockIdx.x;               // 0..2047
    const int b = bt >> 8;

    // ---- Phase 1: joint[u][k] = tanh(hf[bt][k] + hg[b*64+u][k]) -> hi/lo bf16
    {
        const float* hfrow = hf + (size_t)bt * JD;
#pragma unroll
        for (int i = 0; i < 8; ++i) {
            const int task = i * 256 + tid;      // 0..2047
            const int u = task >> 5;             // 0..63
            const int k0 = (task & 31) * 8;      // 0..248
            const float* hgp = hg + ((size_t)(b * UU + u)) * JD + k0;
            float4 f0 = *(const float4*)(hfrow + k0);
            float4 f1 = *(const float4*)(hfrow + k0 + 4);
            float4 g0 = *(const float4*)(hgp);
            float4 g1 = *(const float4*)(hgp + 4);
            float t[8] = {f0.x + g0.x, f0.y + g0.y, f0.z + g0.z, f0.w + g0.w,
                          f1.x + g1.x, f1.y + g1.y, f1.z + g1.z, f1.w + g1.w};
            union { ushort s[8]; uint4 v; } ph, pl;
#pragma unroll
            for (int j = 0; j < 8; ++j) {
                float v = tanhf(t[j]);
                __hip_bfloat16 h = __float2bfloat16(v);
                float hv = __bfloat162float(h);
                ph.s[j] = bf16_bits(v);
                pl.s[j] = bf16_bits(v - hv);
            }
            const int boff = (k0 * 2) ^ ((u & 7) << 4);   // swizzled byte off in row
            *(uint4*)(lds + u * 512 + boff) = ph.v;
            *(uint4*)(lds + 32768 + u * 512 + boff) = pl.v;
        }
    }
    __syncthreads();

    // ---- Phase 2: GEMM ----
    const int lane = tid & 63;
    const int w = tid >> 6;              // wave id 0..3 -> vocab slice
    const int l15 = lane & 15;
    const int lhi = lane >> 4;           // 0..3
    const int swz = (lane & 7) << 4;     // == (row&7)<<4 since rows are m*16+l15

    f32x4 acc[4][8];
#pragma unroll
    for (int m = 0; m < 4; ++m)
#pragma unroll
        for (int n = 0; n < 8; ++n) acc[m][n] = (f32x4){0.f, 0.f, 0.f, 0.f};

    for (int ks = 0; ks < 8; ++ks) {
        bf16x8 Ah[4], Al[4];
        const int off = (ks * 64 + (lhi << 4)) ^ swz;
#pragma unroll
        for (int m = 0; m < 4; ++m) {
            const int row = m * 16 + l15;
            const char* p = lds + row * 512 + off;
            Ah[m] = *(const bf16x8*)p;
            Al[m] = *(const bf16x8*)(p + 32768);
        }
#pragma unroll
        for (int n = 0; n < 8; ++n) {
            const int v = w * 128 + n * 16 + l15;
            const size_t bo = (size_t)v * JD + ks * 32 + (lhi << 3);
            bf16x8 Bh = *(const bf16x8*)(w2h + bo);
            bf16x8 Bl = *(const bf16x8*)(w2l + bo);
#pragma unroll
            for (int m = 0; m < 4; ++m) {
                acc[m][n] = __builtin_amdgcn_mfma_f32_16x16x32_bf16(Ah[m], Bh, acc[m][n], 0, 0, 0);
                acc[m][n] = __builtin_amdgcn_mfma_f32_16x16x32_bf16(Ah[m], Bl, acc[m][n], 0, 0, 0);
                acc[m][n] = __builtin_amdgcn_mfma_f32_16x16x32_bf16(Al[m], Bh, acc[m][n], 0, 0, 0);
            }
        }
    }

    // ---- Epilogue: C[u][v], u = m*16 + lhi*4 + r, v = w*128 + n*16 + l15 ----
    float* ob = out + (size_t)bt * UU * VOCAB;
#pragma unroll
    for (int m = 0; m < 4; ++m) {
#pragma unroll
        for (int n = 0; n < 8; ++n) {
            const int v = w * 128 + n * 16 + l15;
            if (v < VOCAB) {
#pragma unroll
                for (int r = 0; r < 4; ++r) {
                    const int u = m * 16 + lhi * 4 + r;
                    ob[(size_t)u * VOCAB + v] = acc[m][n][r];
                }
            }
        }
    }
}

extern "C" void kernel_launch(void* const* d_in, const int* in_sizes, int n_in,
                              void* d_out, int out_size, void* d_ws, size_t ws_size,
                              hipStream_t stream) {
    const float* ft = (const float*)d_in[0];
    const float* gu = (const float*)d_in[1];
    const float* w1 = (const float*)d_in[2];
    const float* w2 = (const float*)d_in[3];
    float* out = (float*)d_out;

    // ws layout: hf[2048*256] f32 | hg[512*256] f32 | w2h[512*256] bf16 | w2l[...]
    float* hf = (float*)d_ws;
    float* hg = hf + (size_t)BB * TT * JD;                 // +2 MB
    ushort* w2h = (ushort*)(hg + (size_t)BB * UU * JD);    // +0.5 MB
    ushort* w2l = w2h + (size_t)NPAD * JD;                 // +0.25 MB

    joiner_pre<<<BB * TT + BB * UU, 256, 0, stream>>>(ft, gu, w1, hf, hg);
    w2split<<<(NPAD * JD) / 256, 256, 0, stream>>>(w2, w2h, w2l);
    joiner_mfma<<<BB * TT, 256, 0, stream>>>(hf, hg, w2h, w2l, out);
}

// Round 4
// 228.013 us; speedup vs baseline: 3.2502x; 1.0475x over previous
//
#include <hip/hip_runtime.h>
#include <hip/hip_bf16.h>
#include <math.h>

#define ENC 128
#define PRED 256
#define JD 256      // joiner_dim
#define VOCAB 500
#define NPAD 512
#define BB 8
#define TT 256
#define UU 64

typedef __attribute__((ext_vector_type(8))) short bf16x8;
typedef __attribute__((ext_vector_type(4))) float f32x4;

static __device__ __forceinline__ ushort bf16_bits(float x) {
    union { __hip_bfloat16 b; ushort u; } c; c.b = __float2bfloat16(x);
    return c.u;
}
static __device__ __forceinline__ float bits_to_f32(ushort h) {
    union { unsigned u; float f; } c; c.u = ((unsigned)h) << 16;
    return c.f;
}
// branchless tanh: ~8 VALU ops, |err| ~ few ulp (≪ bf16-split error).
// large |x|: e=inf -> 2/inf=0 -> t=1 exactly. x=0 -> 1-2*0.5 = 0 exactly.
static __device__ __forceinline__ float fast_tanh(float x) {
    float ax = fabsf(x);
    float e = __expf(2.0f * ax);
    float t = 1.0f - 2.0f / (e + 1.0f);
    return copysignf(t, x);
}

// ---------------- Kernel A: hf = ft @ w1f^T, hg = gu @ w1g^T (fp32) ----------
__global__ __launch_bounds__(256) void joiner_pre(const float* __restrict__ ft,
                                                  const float* __restrict__ gu,
                                                  const float* __restrict__ w1,
                                                  float* __restrict__ hf,
                                                  float* __restrict__ hg) {
    __shared__ float x[PRED];
    const int row = blockIdx.x;
    const int j = threadIdx.x;   // output column 0..255
    if (row < BB * TT) {
        if (j < ENC) x[j] = ft[row * ENC + j];
        __syncthreads();
        const float* wr = w1 + j * (ENC + PRED);
        float s = 0.f;
#pragma unroll
        for (int k = 0; k < ENC; k += 4) {
            float4 w4 = *(const float4*)(wr + k);
            s += w4.x * x[k] + w4.y * x[k + 1] + w4.z * x[k + 2] + w4.w * x[k + 3];
        }
        hf[row * JD + j] = s;
    } else {
        const int r = row - BB * TT;
        x[j] = gu[r * PRED + j];
        __syncthreads();
        const float* wr = w1 + j * (ENC + PRED) + ENC;
        float s = 0.f;
#pragma unroll
        for (int k = 0; k < PRED; k += 4) {
            float4 w4 = *(const float4*)(wr + k);
            s += w4.x * x[k] + w4.y * x[k + 1] + w4.z * x[k + 2] + w4.w * x[k + 3];
        }
        hg[r * JD + j] = s;
    }
}

// ---------------- Kernel B: split w2 (fp32) -> bf16 hi + bf16 lo, pad to 512 rows
__global__ __launch_bounds__(256) void w2split(const float* __restrict__ w2,
                                               ushort* __restrict__ w2h,
                                               ushort* __restrict__ w2l) {
    const int idx = blockIdx.x * 256 + threadIdx.x;  // 0 .. 512*256-1
    const int row = idx >> 8;
    const int col = idx & 255;
    float x = (row < VOCAB) ? w2[row * JD + col] : 0.f;
    ushort hb = bf16_bits(x);
    w2h[idx] = hb;
    w2l[idx] = bf16_bits(x - bits_to_f32(hb));
}

// ---------------- Kernel C: out = tanh(hf+hg) @ w2^T via split-bf16 MFMA -----
// 512 threads (8 waves) per bt. K processed in two 128-halves so LDS = 32 KB
// (2 blocks/CU, 4 waves/SIMD). Wave w owns vocab slice [w*64, w*64+64).
// Per half: phase1 tanh->bf16 hi/lo into XOR-swizzled LDS; then 16x16x32 MFMA,
// 3 passes (AhBh + AhBl + AlBh), fp32 accumulate across both halves.
__global__ __launch_bounds__(512, 4) void joiner_mfma(const float* __restrict__ hf,
                                                      const float* __restrict__ hg,
                                                      const ushort* __restrict__ w2h,
                                                      const ushort* __restrict__ w2l,
                                                      float* __restrict__ out) {
    __shared__ uint4 ldsv[2048];             // 32 KB: jh @0 (64x256B), jl @16384
    char* lds = (char*)ldsv;

    const int tid = threadIdx.x;
    const int bt = blockIdx.x;               // 0..2047
    const int b = bt >> 8;
    const int lane = tid & 63;
    const int w = tid >> 6;                  // wave 0..7 -> vocab slice base w*64
    const int l15 = lane & 15;
    const int lhi = lane >> 4;               // 0..3

    f32x4 acc[4][4];
#pragma unroll
    for (int m = 0; m < 4; ++m)
#pragma unroll
        for (int n = 0; n < 4; ++n) acc[m][n] = (f32x4){0.f, 0.f, 0.f, 0.f};

    const float* hfrow = hf + (size_t)bt * JD;
    const float* hgb = hg + (size_t)(b * UU) * JD;

    for (int half = 0; half < 2; ++half) {
        const int k0 = half * 128;
        if (half) __syncthreads();           // all waves done reading prev half
        // ---- Phase 1: joint[u][k0..k0+128) -> bf16 hi/lo, swizzled ----
#pragma unroll
        for (int i = 0; i < 2; ++i) {
            const int task = i * 512 + tid;  // 0..1023
            const int u = task >> 4;         // 0..63
            const int kl = (task & 15) * 8;  // 0..120 (local k)
            const float* fp = hfrow + k0 + kl;
            const float* gp = hgb + (size_t)u * JD + k0 + kl;
            float4 f0 = *(const float4*)fp;
            float4 f1 = *(const float4*)(fp + 4);
            float4 g0 = *(const float4*)gp;
            float4 g1 = *(const float4*)(gp + 4);
            float t[8] = {f0.x + g0.x, f0.y + g0.y, f0.z + g0.z, f0.w + g0.w,
                          f1.x + g1.x, f1.y + g1.y, f1.z + g1.z, f1.w + g1.w};
            union { ushort s[8]; uint4 v; } ph, pl;
#pragma unroll
            for (int j = 0; j < 8; ++j) {
                float v = fast_tanh(t[j]);
                ushort hb = bf16_bits(v);
                ph.s[j] = hb;
                pl.s[j] = bf16_bits(v - bits_to_f32(hb));
            }
            const int boff = (kl * 2) ^ ((u & 7) << 4);
            *(uint4*)(lds + u * 256 + boff) = ph.v;
            *(uint4*)(lds + 16384 + u * 256 + boff) = pl.v;
        }
        __syncthreads();

        // ---- Phase 2: GEMM over this K-half (4 steps of K=32) ----
#pragma unroll
        for (int ks = 0; ks < 4; ++ks) {
            bf16x8 Ah[4], Al[4];
            const int off = (ks * 64 + lhi * 16) ^ ((l15 & 7) << 4);
#pragma unroll
            for (int m = 0; m < 4; ++m) {
                const char* p = lds + (m * 16 + l15) * 256 + off;   // row&7 == l15&7
                Ah[m] = *(const bf16x8*)p;
                Al[m] = *(const bf16x8*)(p + 16384);
            }
#pragma unroll
            for (int n = 0; n < 4; ++n) {
                const int v = w * 64 + n * 16 + l15;
                const size_t bo = (size_t)v * JD + k0 + ks * 32 + lhi * 8;
                bf16x8 Bh = *(const bf16x8*)(w2h + bo);
                bf16x8 Bl = *(const bf16x8*)(w2l + bo);
#pragma unroll
                for (int m = 0; m < 4; ++m) {
                    acc[m][n] = __builtin_amdgcn_mfma_f32_16x16x32_bf16(Ah[m], Bh, acc[m][n], 0, 0, 0);
                    acc[m][n] = __builtin_amdgcn_mfma_f32_16x16x32_bf16(Ah[m], Bl, acc[m][n], 0, 0, 0);
                    acc[m][n] = __builtin_amdgcn_mfma_f32_16x16x32_bf16(Al[m], Bh, acc[m][n], 0, 0, 0);
                }
            }
        }
    }

    // ---- Epilogue: u = m*16 + lhi*4 + r, v = w*64 + n*16 + l15 ----
    float* ob = out + (size_t)bt * UU * VOCAB;
#pragma unroll
    for (int n = 0; n < 4; ++n) {
        const int v = w * 64 + n * 16 + l15;
        if (v < VOCAB) {
#pragma unroll
            for (int m = 0; m < 4; ++m) {
#pragma unroll
                for (int r = 0; r < 4; ++r) {
                    const int u = m * 16 + lhi * 4 + r;
                    ob[(size_t)u * VOCAB + v] = acc[m][n][r];
                }
            }
        }
    }
}

extern "C" void kernel_launch(void* const* d_in, const int* in_sizes, int n_in,
                              void* d_out, int out_size, void* d_ws, size_t ws_size,
                              hipStream_t stream) {
    const float* ft = (const float*)d_in[0];
    const float* gu = (const float*)d_in[1];
    const float* w1 = (const float*)d_in[2];
    const float* w2 = (const float*)d_in[3];
    float* out = (float*)d_out;

    // ws layout: hf[2048*256] f32 | hg[512*256] f32 | w2h[512*256] bf16 | w2l[...]
    float* hf = (float*)d_ws;
    float* hg = hf + (size_t)BB * TT * JD;                 // +2 MB
    ushort* w2h = (ushort*)(hg + (size_t)BB * UU * JD);    // +0.5 MB
    ushort* w2l = w2h + (size_t)NPAD * JD;                 // +0.25 MB

    joiner_pre<<<BB * TT + BB * UU, 256, 0, stream>>>(ft, gu, w1, hf, hg);
    w2split<<<(NPAD * JD) / 256, 256, 0, stream>>>(w2, w2h, w2l);
    joiner_mfma<<<BB * TT, 512, 0, stream>>>(hf, hg, w2h, w2l, out);
}

// Round 5
// 163.443 us; speedup vs baseline: 4.5343x; 1.3951x over previous
//
#include <hip/hip_runtime.h>
#include <math.h>

#define ENC 128
#define PRED 256
#define JD 256      // joiner_dim
#define VOCAB 500
#define NPAD 512
#define BB 8
#define TT 256
#define UU 64

typedef __attribute__((ext_vector_type(8))) _Float16 f16x8;
typedef __attribute__((ext_vector_type(4))) float f32x4;

// branchless tanh: ~8 VALU ops, |err| few ulp (≪ fp16 quantization error).
static __device__ __forceinline__ float fast_tanh(float x) {
    float ax = fabsf(x);
    float e = __expf(2.0f * ax);
    float t = 1.0f - 2.0f / (e + 1.0f);
    return copysignf(t, x);
}

// ---- Kernel A: hf = ft@w1f^T (rows 0..2047), hg = gu@w1g^T (2048..2559),
//                w2f = fp16(w2) padded to 512 rows (2560..3071) ----
__global__ __launch_bounds__(256) void joiner_pre(const float* __restrict__ ft,
                                                  const float* __restrict__ gu,
                                                  const float* __restrict__ w1,
                                                  const float* __restrict__ w2,
                                                  float* __restrict__ hf,
                                                  float* __restrict__ hg,
                                                  _Float16* __restrict__ w2f) {
    __shared__ float x[PRED];
    const int row = blockIdx.x;
    const int j = threadIdx.x;   // 0..255
    if (row < BB * TT) {
        if (j < ENC) x[j] = ft[row * ENC + j];
        __syncthreads();
        const float* wr = w1 + j * (ENC + PRED);
        float s = 0.f;
#pragma unroll
        for (int k = 0; k < ENC; k += 4) {
            float4 w4 = *(const float4*)(wr + k);
            s += w4.x * x[k] + w4.y * x[k + 1] + w4.z * x[k + 2] + w4.w * x[k + 3];
        }
        hf[row * JD + j] = s;
    } else if (row < BB * TT + BB * UU) {
        const int r = row - BB * TT;
        x[j] = gu[r * PRED + j];
        __syncthreads();
        const float* wr = w1 + j * (ENC + PRED) + ENC;
        float s = 0.f;
#pragma unroll
        for (int k = 0; k < PRED; k += 4) {
            float4 w4 = *(const float4*)(wr + k);
            s += w4.x * x[k] + w4.y * x[k + 1] + w4.z * x[k + 2] + w4.w * x[k + 3];
        }
        hg[r * JD + j] = s;
    } else {
        const int r = row - (BB * TT + BB * UU);   // 0..511
        float v = (r < VOCAB) ? w2[r * JD + j] : 0.f;
        w2f[r * JD + j] = (_Float16)v;
    }
}

// ---- Kernel B: out = tanh(hf+hg) @ w2^T, single-pass fp16 MFMA ----
// 512 threads (8 waves) per bt. joint 64x256 fp16 in 32 KB XOR-swizzled LDS,
// ONE barrier, then 8 K-steps of 16x16x32 f16 MFMA. Wave w owns v-slice
// [w*64, w*64+64). acc fp32.
__global__ __launch_bounds__(512, 4) void joiner_mfma(const float* __restrict__ hf,
                                                      const float* __restrict__ hg,
                                                      const _Float16* __restrict__ w2f,
                                                      float* __restrict__ out) {
    __shared__ uint4 ldsv[2048];             // 32 KB: 64 rows x 512 B
    char* lds = (char*)ldsv;

    const int tid = threadIdx.x;
    const int bt = blockIdx.x;               // 0..2047
    const int b = bt >> 8;
    const int lane = tid & 63;
    const int w = tid >> 6;                  // wave 0..7 -> v base w*64
    const int l15 = lane & 15;
    const int lhi = lane >> 4;               // 0..3

    const float* hfrow = hf + (size_t)bt * JD;
    const float* hgb = hg + (size_t)(b * UU) * JD;

    // ---- Phase 1: joint[u][k] = tanh(hf[k] + hg[u][k]) -> fp16, swizzled ----
#pragma unroll
    for (int i = 0; i < 4; ++i) {
        const int task = i * 512 + tid;      // 0..2047
        const int u = task >> 5;             // 0..63
        const int kl = (task & 31) * 8;      // 0..248
        const float* fp = hfrow + kl;
        const float* gp = hgb + (size_t)u * JD + kl;
        float4 f0 = *(const float4*)fp;
        float4 f1 = *(const float4*)(fp + 4);
        float4 g0 = *(const float4*)gp;
        float4 g1 = *(const float4*)(gp + 4);
        float t[8] = {f0.x + g0.x, f0.y + g0.y, f0.z + g0.z, f0.w + g0.w,
                      f1.x + g1.x, f1.y + g1.y, f1.z + g1.z, f1.w + g1.w};
        union { _Float16 h[8]; uint4 v; } p;
#pragma unroll
        for (int j = 0; j < 8; ++j) p.h[j] = (_Float16)fast_tanh(t[j]);
        const int boff = (kl * 2) ^ ((u & 7) << 4);
        *(uint4*)(lds + u * 512 + boff) = p.v;
    }
    __syncthreads();

    // ---- Phase 2: GEMM, 8 K-steps of 32 ----
    f32x4 acc[4][4];
#pragma unroll
    for (int m = 0; m < 4; ++m)
#pragma unroll
        for (int n = 0; n < 4; ++n) acc[m][n] = (f32x4){0.f, 0.f, 0.f, 0.f};

#pragma unroll
    for (int ks = 0; ks < 8; ++ks) {
        f16x8 A[4];
        const int off = (ks * 64 + lhi * 16) ^ ((l15 & 7) << 4);
#pragma unroll
        for (int m = 0; m < 4; ++m)
            A[m] = *(const f16x8*)(lds + (m * 16 + l15) * 512 + off);
#pragma unroll
        for (int n = 0; n < 4; ++n) {
            const int v = w * 64 + n * 16 + l15;
            f16x8 B = *(const f16x8*)(w2f + (size_t)v * JD + ks * 32 + lhi * 8);
#pragma unroll
            for (int m = 0; m < 4; ++m)
                acc[m][n] = __builtin_amdgcn_mfma_f32_16x16x32_f16(A[m], B, acc[m][n], 0, 0, 0);
        }
    }

    // ---- Epilogue: u = m*16 + lhi*4 + r, v = w*64 + n*16 + l15 ----
    float* ob = out + (size_t)bt * UU * VOCAB;
#pragma unroll
    for (int n = 0; n < 4; ++n) {
        const int v = w * 64 + n * 16 + l15;
        if (v < VOCAB) {
#pragma unroll
            for (int m = 0; m < 4; ++m) {
#pragma unroll
                for (int r = 0; r < 4; ++r) {
                    const int u = m * 16 + lhi * 4 + r;
                    ob[(size_t)u * VOCAB + v] = acc[m][n][r];
                }
            }
        }
    }
}

extern "C" void kernel_launch(void* const* d_in, const int* in_sizes, int n_in,
                              void* d_out, int out_size, void* d_ws, size_t ws_size,
                              hipStream_t stream) {
    const float* ft = (const float*)d_in[0];
    const float* gu = (const float*)d_in[1];
    const float* w1 = (const float*)d_in[2];
    const float* w2 = (const float*)d_in[3];
    float* out = (float*)d_out;

    // ws: hf[2048*256] f32 | hg[512*256] f32 | w2f[512*256] fp16
    float* hf = (float*)d_ws;
    float* hg = hf + (size_t)BB * TT * JD;
    _Float16* w2f = (_Float16*)(hg + (size_t)BB * UU * JD);

    joiner_pre<<<BB * TT + BB * UU + NPAD, 256, 0, stream>>>(ft, gu, w1, w2, hf, hg, w2f);
    joiner_mfma<<<BB * TT, 512, 0, stream>>>(hf, hg, w2f, out);
}

// Round 8
// 157.229 us; speedup vs baseline: 4.7135x; 1.0395x over previous
//
#include <hip/hip_runtime.h>
#include <math.h>

#define ENC 128
#define PRED 256
#define JD 256      // joiner_dim
#define VOCAB 500
#define NPAD 512
#define BB 8
#define TT 256
#define UU 64

typedef __attribute__((ext_vector_type(8))) _Float16 f16x8;
typedef __attribute__((ext_vector_type(4))) float f32x4;

// branchless tanh: ~8 VALU ops, |err| few ulp (≪ fp16 quantization error).
static __device__ __forceinline__ float fast_tanh(float x) {
    float ax = fabsf(x);
    float e = __expf(2.0f * ax);
    float t = 1.0f - 2.0f / (e + 1.0f);
    return copysignf(t, x);
}

// ---- Kernel A: hf = ft@w1f^T (rows 0..2047), hg = gu@w1g^T (2048..2559),
//                w2f = fp16(w2) padded to 512 rows (2560..3071) ----
__global__ __launch_bounds__(256) void joiner_pre(const float* __restrict__ ft,
                                                  const float* __restrict__ gu,
                                                  const float* __restrict__ w1,
                                                  const float* __restrict__ w2,
                                                  float* __restrict__ hf,
                                                  float* __restrict__ hg,
                                                  _Float16* __restrict__ w2f) {
    __shared__ float x[PRED];
    const int row = blockIdx.x;
    const int j = threadIdx.x;   // 0..255
    if (row < BB * TT) {
        if (j < ENC) x[j] = ft[row * ENC + j];
        __syncthreads();
        const float* wr = w1 + j * (ENC + PRED);
        float s = 0.f;
#pragma unroll
        for (int k = 0; k < ENC; k += 4) {
            float4 w4 = *(const float4*)(wr + k);
            s += w4.x * x[k] + w4.y * x[k + 1] + w4.z * x[k + 2] + w4.w * x[k + 3];
        }
        hf[row * JD + j] = s;
    } else if (row < BB * TT + BB * UU) {
        const int r = row - BB * TT;
        x[j] = gu[r * PRED + j];
        __syncthreads();
        const float* wr = w1 + j * (ENC + PRED) + ENC;
        float s = 0.f;
#pragma unroll
        for (int k = 0; k < PRED; k += 4) {
            float4 w4 = *(const float4*)(wr + k);
            s += w4.x * x[k] + w4.y * x[k + 1] + w4.z * x[k + 2] + w4.w * x[k + 3];
        }
        hg[r * JD + j] = s;
    } else {
        const int r = row - (BB * TT + BB * UU);   // 0..511
        float v = (r < VOCAB) ? w2[r * JD + j] : 0.f;
        w2f[r * JD + j] = (_Float16)v;
    }
}

// ---- Kernel B: out = tanh(hf+hg) @ w2^T, single-pass fp16 MFMA ----
// 512 threads (8 waves) per bt. joint 64x256 fp16 in XOR-swizzled LDS (32 KB),
// one barrier, 8 K-steps of 16x16x32 f16 MFMA (wave w owns v in [w*64,w*64+64)),
// then coalesced epilogue: per m-quadrant, fragments -> LDS [16][516] f32,
// barrier, 512 threads stream f32x4 nontemporal stores.
__global__ __launch_bounds__(512, 4) void joiner_mfma(const float* __restrict__ hf,
                                                      const float* __restrict__ hg,
                                                      const _Float16* __restrict__ w2f,
                                                      float* __restrict__ out) {
    __shared__ char lds[33024];              // max(joint 32768, epi 16*516*4)

    const int tid = threadIdx.x;
    const int bt = blockIdx.x;               // 0..2047
    const int b = bt >> 8;
    const int lane = tid & 63;
    const int w = tid >> 6;                  // wave 0..7 -> v base w*64
    const int l15 = lane & 15;
    const int lhi = lane >> 4;               // 0..3

    const float* hfrow = hf + (size_t)bt * JD;
    const float* hgb = hg + (size_t)(b * UU) * JD;

    // ---- Phase 1: joint[u][k] = tanh(hf[k] + hg[u][k]) -> fp16, swizzled ----
#pragma unroll
    for (int i = 0; i < 4; ++i) {
        const int task = i * 512 + tid;      // 0..2047
        const int u = task >> 5;             // 0..63
        const int kl = (task & 31) * 8;      // 0..248
        const float* fp = hfrow + kl;
        const float* gp = hgb + (size_t)u * JD + kl;
        float4 f0 = *(const float4*)fp;
        float4 f1 = *(const float4*)(fp + 4);
        float4 g0 = *(const float4*)gp;
        float4 g1 = *(const float4*)(gp + 4);
        float t[8] = {f0.x + g0.x, f0.y + g0.y, f0.z + g0.z, f0.w + g0.w,
                      f1.x + g1.x, f1.y + g1.y, f1.z + g1.z, f1.w + g1.w};
        union { _Float16 h[8]; uint4 v; } p;
#pragma unroll
        for (int j = 0; j < 8; ++j) p.h[j] = (_Float16)fast_tanh(t[j]);
        const int boff = (kl * 2) ^ ((u & 7) << 4);
        *(uint4*)(lds + u * 512 + boff) = p.v;
    }
    __syncthreads();

    // ---- Phase 2: GEMM, 8 K-steps of 32 ----
    f32x4 acc[4][4];
#pragma unroll
    for (int m = 0; m < 4; ++m)
#pragma unroll
        for (int n = 0; n < 4; ++n) acc[m][n] = (f32x4){0.f, 0.f, 0.f, 0.f};

#pragma unroll
    for (int ks = 0; ks < 8; ++ks) {
        f16x8 A[4];
        const int off = (ks * 64 + lhi * 16) ^ ((l15 & 7) << 4);
#pragma unroll
        for (int m = 0; m < 4; ++m)
            A[m] = *(const f16x8*)(lds + (m * 16 + l15) * 512 + off);
#pragma unroll
        for (int n = 0; n < 4; ++n) {
            const int v = w * 64 + n * 16 + l15;
            f16x8 B = *(const f16x8*)(w2f + (size_t)v * JD + ks * 32 + lhi * 8);
#pragma unroll
            for (int m = 0; m < 4; ++m)
                acc[m][n] = __builtin_amdgcn_mfma_f32_16x16x32_f16(A[m], B, acc[m][n], 0, 0, 0);
        }
    }

    // ---- Epilogue: per m-quadrant, LDS transpose -> coalesced f32x4 stores --
    // fragment element: u = m*16 + lhi*4 + r, v = w*64 + n*16 + l15
    float* ebuf = (float*)lds;               // viewed as [16][516] f32
    float* ob = out + (size_t)bt * UU * VOCAB;
#pragma unroll
    for (int m = 0; m < 4; ++m) {
        __syncthreads();                     // LDS free (joint reads / prev chunk done)
#pragma unroll
        for (int n = 0; n < 4; ++n) {
            const int col = w * 64 + n * 16 + l15;
#pragma unroll
            for (int r = 0; r < 4; ++r)
                ebuf[(lhi * 4 + r) * 516 + col] = acc[m][n][r];
        }
        __syncthreads();
#pragma unroll
        for (int it = 0; it < 4; ++it) {
            const int idx = it * 512 + tid;  // 0..2047
            const int row = idx >> 7;        // 0..15
            const int c4 = idx & 127;        // float4 index in row
            if (c4 < 125) {                  // 125*4 = 500 cols exactly
                f32x4 vv = *(const f32x4*)(ebuf + row * 516 + c4 * 4);
                const int u = m * 16 + row;
                __builtin_nontemporal_store(vv, (f32x4*)(ob + (size_t)u * VOCAB + c4 * 4));
            }
        }
    }
}

extern "C" void kernel_launch(void* const* d_in, const int* in_sizes, int n_in,
                              void* d_out, int out_size, void* d_ws, size_t ws_size,
                              hipStream_t stream) {
    const float* ft = (const float*)d_in[0];
    const float* gu = (const float*)d_in[1];
    const float* w1 = (const float*)d_in[2];
    const float* w2 = (const float*)d_in[3];
    float* out = (float*)d_out;

    // ws: hf[2048*256] f32 | hg[512*256] f32 | w2f[512*256] fp16
    float* hf = (float*)d_ws;
    float* hg = hf + (size_t)BB * TT * JD;
    _Float16* w2f = (_Float16*)(hg + (size_t)BB * UU * JD);

    joiner_pre<<<BB * TT + BB * UU + NPAD, 256, 0, stream>>>(ft, gu, w1, w2, hf, hg, w2f);
    joiner_mfma<<<BB * TT, 512, 0, stream>>>(hf, hg, w2f, out);
}